// Round 1
// 2799.971 us; speedup vs baseline: 1.0111x; 1.0111x over previous
//
#include <hip/hip_runtime.h>
#include <hip/hip_bf16.h>
#include <cstdint>
#include <cstddef>

// Problem constants
#define T_TOK 4096
#define HID   4096
#define INT_  14336
#define RNK   318
#define RP    384     // rank padded to multiple of 128 (N) / 64 (K)

typedef __hip_bfloat16 bf16;
typedef __attribute__((ext_vector_type(8))) __bf16 bf16x8;
typedef __attribute__((ext_vector_type(4))) float  f32x4;

// ---------------------------------------------------------------------------
// async global->LDS, 16B per lane. LDS dest is wave-uniform base + lane*16.
__device__ __forceinline__ void gload16(const bf16* g, void* l) {
  __builtin_amdgcn_global_load_lds(
      (__attribute__((address_space(1))) void*)(uintptr_t)(const void*)g,
      (__attribute__((address_space(3))) void*)l,
      16, 0, 0);
}

// raw barrier: NO implicit vmcnt(0) drain (unlike __syncthreads), but with
// compiler-level memory fences so LDS reads/stage issues can't cross it.
__device__ __forceinline__ void wg_barrier() {
  asm volatile("" ::: "memory");
  __builtin_amdgcn_s_barrier();
  asm volatile("" ::: "memory");
}

// ---------------------------------------------------------------------------
// fp32 -> bf16 bulk convert (n divisible by 4)
__global__ void k_convert(const float* __restrict__ s, bf16* __restrict__ d, long n) {
  long i = ((long)blockIdx.x * blockDim.x + threadIdx.x) * 4;
  long stride = (long)gridDim.x * blockDim.x * 4;
  for (; i < n; i += stride) {
    float4 v = *(const float4*)(s + i);
    __hip_bfloat162 p0 = __float22bfloat162_rn(make_float2(v.x, v.y));
    __hip_bfloat162 p1 = __float22bfloat162_rn(make_float2(v.z, v.w));
    *(__hip_bfloat162*)(d + i)     = p0;
    *(__hip_bfloat162*)(d + i + 2) = p1;
  }
}

// fp32 -> bf16 with zero-padding to (dst_rows x dcols) from (srows x scols)
__global__ void k_convert_pad(const float* __restrict__ s, bf16* __restrict__ d,
                              int srows, int scols, int dcols, long total) {
  long i = (long)blockIdx.x * blockDim.x + threadIdx.x;
  long stride = (long)gridDim.x * blockDim.x;
  for (; i < total; i += stride) {
    int r = (int)(i / dcols), c = (int)(i % dcols);
    float v = (r < srows && c < scols) ? s[(long)r * scols + c] : 0.f;
    d[i] = __float2bfloat16(v);
  }
}

// ---------------------------------------------------------------------------
// OLD 128x128 kernel (m97 structure) — kept for the small-N (RP=384) GEMMs.
template <int EPI>
__global__ __launch_bounds__(256)
void k_gemm(const bf16* __restrict__ A0, const bf16* __restrict__ B0, int K0,
            const bf16* __restrict__ A1, const bf16* __restrict__ B1, int K1,
            int N, void* __restrict__ Cout, const bf16* __restrict__ Up) {
  __shared__ __align__(128) bf16 As[128 * 64];
  __shared__ __align__(128) bf16 Bs[128 * 64];

  const int tid  = threadIdx.x;
  const int wv   = tid >> 6;
  const int lane = tid & 63;
  const int quad = lane >> 4;
  const int m16  = lane & 15;
  const int row0 = blockIdx.y * 128;
  const int col0 = blockIdx.x * 128;
  const int wrow = (wv >> 1) * 64;
  const int wcol = (wv & 1) * 64;

  const int srow = lane >> 3;
  const int sq   = (lane & 7) ^ srow;

  int a_off[4], b_off[4];
#pragma unroll
  for (int i = 0; i < 4; i++) {
    int r = wrow + i * 16 + m16;
    a_off[i] = r * 128 + ((quad ^ (r & 7)) << 4);
    int c = wcol + i * 16 + m16;
    b_off[i] = c * 128 + ((quad ^ (c & 7)) << 4);
  }

  f32x4 acc[4][4] = {};

  const bf16* Aseg = A0;
  const bf16* Bseg = B0;
  int Ks = K0;
#pragma unroll 1
  for (int seg = 0; seg < 2; seg++) {
    if (seg) {
      if (K1 == 0) break;
      Aseg = A1; Bseg = B1; Ks = K1;
    }
    const int nkb = Ks >> 6;
#pragma unroll 1
    for (int kb = 0; kb < nkb; kb++) {
      __syncthreads();
#pragma unroll
      for (int i = 0; i < 4; i++) {
        const int wl = (wv << 2) + i;
        const int r  = (wl << 3) + srow;
        gload16(Aseg + (size_t)(row0 + r) * Ks + (kb << 6) + (sq << 3),
                (char*)As + wl * 1024);
        gload16(Bseg + (size_t)(col0 + r) * Ks + (kb << 6) + (sq << 3),
                (char*)Bs + wl * 1024);
      }
      __syncthreads();
#pragma unroll
      for (int s = 0; s < 2; s++) {
        bf16x8 af[4], bfr[4];
#pragma unroll
        for (int i = 0; i < 4; i++)
          af[i] = *(const bf16x8*)((const char*)As + (a_off[i] ^ (s << 6)));
#pragma unroll
        for (int j = 0; j < 4; j++)
          bfr[j] = *(const bf16x8*)((const char*)Bs + (b_off[j] ^ (s << 6)));
#pragma unroll
        for (int i = 0; i < 4; i++)
#pragma unroll
          for (int j = 0; j < 4; j++)
            acc[i][j] = __builtin_amdgcn_mfma_f32_16x16x32_bf16(
                af[i], bfr[j], acc[i][j], 0, 0, 0);
      }
    }
  }

#pragma unroll
  for (int i = 0; i < 4; i++) {
#pragma unroll
    for (int j = 0; j < 4; j++) {
      const int cc = col0 + wcol + j * 16 + m16;
#pragma unroll
      for (int r = 0; r < 4; r++) {
        const int rr = row0 + wrow + i * 16 + quad * 4 + r;
        const size_t idx = (size_t)rr * N + cc;
        float v = acc[i][j][r];
        if (EPI == 0) {
          ((bf16*)Cout)[idx] = __float2bfloat16(v);
        } else if (EPI == 1) {
          float u  = __bfloat162float(Up[idx]);
          float sg = v / (1.f + __expf(-v));
          ((bf16*)Cout)[idx] = __float2bfloat16(sg * u);
        } else {
          ((float*)Cout)[idx] = v;
        }
      }
    }
  }
}

// ---------------------------------------------------------------------------
// NEW 256x256 8-phase kernel (T3+T4 counted vmcnt, T5 setprio).
// 512 threads = 8 waves (2M x 4N); per-wave 128x64 output; BK=64;
// LDS 128 KiB double-buffered. One vmcnt(4) per K-tile, never vmcnt(0)
// in the main loop. Region-safety proven by barrier ordering:
//   buf regions:  A-mh0 read only in ph1 (held to ph2), A-mh1 in ph3,
//                 B-nh0 only in ph1 (held to ph3), B-nh1 only in ph2 (held).
//   stage plan:   ph1 -> (t+1).B1,(t+1).A1 into buf^1 (dead since t-1)
//                 ph3 -> (t+2).B0 into buf   (dead after this ph1)
//                 ph4 -> (t+2).A0 into buf   (dead after this ph1)
// vmcnt(4) at ph4 leaves exactly (t+2).B0/A0 (4 loads) in flight and
// guarantees tile t+1 fully landed for the next iteration.
#define MMA_Q(MI0, NJ0, BFR)                                                   \
  do {                                                                         \
    __builtin_amdgcn_s_setprio(1);                                             \
    _Pragma("unroll")                                                          \
    for (int i = 0; i < 4; i++)                                                \
      _Pragma("unroll")                                                        \
      for (int j = 0; j < 2; j++)                                              \
        _Pragma("unroll")                                                      \
        for (int ks = 0; ks < 2; ks++)                                         \
          acc[(MI0) + i][(NJ0) + j] = __builtin_amdgcn_mfma_f32_16x16x32_bf16( \
              af[i][ks], BFR[j][ks], acc[(MI0) + i][(NJ0) + j], 0, 0, 0);      \
    __builtin_amdgcn_s_setprio(0);                                             \
  } while (0)

template <int EPI>
__global__ __launch_bounds__(512)
void k_gemm256(const bf16* __restrict__ Am, const bf16* __restrict__ Bm, int K0,
               const bf16* __restrict__ Ad, const bf16* __restrict__ Bd, int K1,
               int N, void* __restrict__ Cout, const bf16* __restrict__ Up) {
  __shared__ __align__(128) bf16 As[2][256 * 64];   // 64 KiB
  __shared__ __align__(128) bf16 Bs[2][256 * 64];   // 64 KiB

  const int tid  = threadIdx.x;
  const int wv   = tid >> 6;
  const int lane = tid & 63;
  const int quad = lane >> 4;
  const int m16  = lane & 15;
  const int wm   = wv >> 2;      // 0..1  (M warp)
  const int wn   = wv & 3;       // 0..3  (N warp)

  // XCD-contiguous block swizzle; grid sizes here are 896 and 256 (%8==0).
  int lin = blockIdx.y * gridDim.x + blockIdx.x;
  const int nwg = gridDim.x * gridDim.y;
  lin = (lin & 7) * (nwg >> 3) + (lin >> 3);
  const int row0 = (lin / gridDim.x) * 256;
  const int col0 = (lin % gridDim.x) * 256;

  // staging lane mapping (16B chunks, XOR swizzle on source, linear LDS dest)
  const int srow = lane >> 3;                 // 0..7
  const int sq8  = ((lane & 7) ^ srow) << 3;  // swizzled K element offset
  const int arow = row0 + wv * 8 + srow;      // + (b*128 + mh*64)
  const int brow = col0 + wm * 64 + wn * 8 + srow;  // + (b*128 + h*32)
  const int a_dst = wv * 8 * 128;                   // LDS byte base (wave-uniform)
  const int b_dst = (wm * 64 + wn * 8) * 128;

  const int nkb0 = K0 >> 6;
  const int nkb  = nkb0 + (K1 >> 6);          // even for all our shapes

  auto stA = [&](int tt, int mh) {            // 2 loads: units (mh, b=0/1)
    const int bb = tt & 1;                    // buffer from UNwrapped index
    if (tt >= nkb) tt -= nkb;                 // tail wrap: garbage into dead regions
    const bf16* S; int K, kc;
    if (tt < nkb0) { S = Am; K = K0; kc = tt << 6; }
    else           { S = Ad; K = K1; kc = (tt - nkb0) << 6; }
#pragma unroll
    for (int b = 0; b < 2; b++) {
      const int roff = b * 128 + mh * 64;
      gload16(S + (size_t)(arow + roff) * K + kc + sq8,
              (char*)As[bb] + a_dst + roff * 128);
    }
  };
  auto stB = [&](int tt, int h) {             // 2 loads: units (h, b=0/1)
    const int bb = tt & 1;
    if (tt >= nkb) tt -= nkb;
    const bf16* S; int K, kc;
    if (tt < nkb0) { S = Bm; K = K0; kc = tt << 6; }
    else           { S = Bd; K = K1; kc = (tt - nkb0) << 6; }
#pragma unroll
    for (int b = 0; b < 2; b++) {
      const int roff = b * 128 + h * 32;
      gload16(S + (size_t)(brow + roff) * K + kc + sq8,
              (char*)Bs[bb] + b_dst + roff * 128);
    }
  };

  // ds_read fragment byte offsets (mh0 / nh0; other halves at +8192 / +4096)
  int a_off[4], b_off[2];
#pragma unroll
  for (int i = 0; i < 4; i++) {
    const int r = wm * 128 + i * 16 + m16;
    a_off[i] = r * 128 + ((quad ^ (r & 7)) << 4);
  }
#pragma unroll
  for (int j = 0; j < 2; j++) {
    const int r = wn * 64 + j * 16 + m16;
    b_off[j] = r * 128 + ((quad ^ (r & 7)) << 4);
  }

  f32x4 acc[8][4] = {};
  bf16x8 af[4][2], bq0[2][2], bq1[2][2];

  // prologue: tile0 fully + tile1's B0/A0; wait leaves tile1's 4 in flight
  stB(0, 0); stA(0, 0); stB(0, 1); stA(0, 1);
  stB(1, 0); stA(1, 0);
  asm volatile("s_waitcnt vmcnt(4)" ::: "memory");
  wg_barrier();

#pragma unroll 1
  for (int t = 0; t < nkb; ++t) {
    const char* Ab = (const char*)As[t & 1];
    const char* Bb = (const char*)Bs[t & 1];

    // ---- phase 1: Q(m0,n0) — 12 ds_reads, stage (t+1).B1 + (t+1).A1 ----
#pragma unroll
    for (int i = 0; i < 4; i++)
#pragma unroll
      for (int ks = 0; ks < 2; ks++)
        af[i][ks] = *(const bf16x8*)(Ab + (a_off[i] ^ (ks << 6)));
#pragma unroll
    for (int j = 0; j < 2; j++)
#pragma unroll
      for (int ks = 0; ks < 2; ks++)
        bq0[j][ks] = *(const bf16x8*)(Bb + (b_off[j] ^ (ks << 6)));
    stB(t + 1, 1); stA(t + 1, 1);
    wg_barrier();
    MMA_Q(0, 0, bq0);
    wg_barrier();

    // ---- phase 2: Q(m0,n1) — 4 ds_reads (A mh0 held) ----
#pragma unroll
    for (int j = 0; j < 2; j++)
#pragma unroll
      for (int ks = 0; ks < 2; ks++)
        bq1[j][ks] = *(const bf16x8*)(Bb + ((b_off[j] + 4096) ^ (ks << 6)));
    wg_barrier();
    MMA_Q(0, 2, bq1);
    wg_barrier();

    // ---- phase 3: Q(m1,n0) — 8 ds_reads (B nh0 held), stage (t+2).B0 ----
#pragma unroll
    for (int i = 0; i < 4; i++)
#pragma unroll
      for (int ks = 0; ks < 2; ks++)
        af[i][ks] = *(const bf16x8*)(Ab + ((a_off[i] + 8192) ^ (ks << 6)));
    stB(t + 2, 0);
    wg_barrier();
    MMA_Q(4, 0, bq0);
    wg_barrier();

    // ---- phase 4: Q(m1,n1) — 0 ds_reads, stage (t+2).A0, counted wait ----
    stA(t + 2, 0);
    asm volatile("s_waitcnt vmcnt(4)" ::: "memory");
    wg_barrier();
    MMA_Q(4, 2, bq1);
    wg_barrier();
  }

  // drain LDS-DMA before endpgm / epilogue
  asm volatile("s_waitcnt vmcnt(0)" ::: "memory");

  // Epilogue. C/D layout: col = lane&15, row = quad*4 + r  [m89-verified]
#pragma unroll
  for (int mi = 0; mi < 8; mi++) {
#pragma unroll
    for (int nj = 0; nj < 4; nj++) {
      const int cc = col0 + wn * 64 + nj * 16 + m16;
#pragma unroll
      for (int r = 0; r < 4; r++) {
        const int rr = row0 + wm * 128 + mi * 16 + quad * 4 + r;
        const size_t idx = (size_t)rr * N + cc;
        float v = acc[mi][nj][r];
        if (EPI == 0) {
          ((bf16*)Cout)[idx] = __float2bfloat16(v);
        } else if (EPI == 1) {
          float u  = __bfloat162float(Up[idx]);
          float sg = v / (1.f + __expf(-v));
          ((bf16*)Cout)[idx] = __float2bfloat16(sg * u);
        } else {
          ((float*)Cout)[idx] = v;
        }
      }
    }
  }
}

// ---------------------------------------------------------------------------
extern "C" void kernel_launch(void* const* d_in, const int* in_sizes, int n_in,
                              void* d_out, int out_size, void* d_ws, size_t ws_size,
                              hipStream_t stream) {
  const float* x   = (const float*)d_in[0];
  const float* W1  = (const float*)d_in[1];
  const float* W2  = (const float*)d_in[2];
  const float* W3  = (const float*)d_in[3];
  const float* du1 = (const float*)d_in[4];
  const float* dv1 = (const float*)d_in[5];
  const float* du2 = (const float*)d_in[6];
  const float* dv2 = (const float*)d_in[7];
  const float* du3 = (const float*)d_in[8];
  const float* dv3 = (const float*)d_in[9];

  bf16* p = (bf16*)d_ws;
  bf16* xb   = p; p += (size_t)T_TOK * HID;
  bf16* W1b  = p; p += (size_t)INT_ * HID;
  bf16* W2b  = p; p += (size_t)HID * INT_;
  bf16* W3b  = p; p += (size_t)INT_ * HID;
  bf16* du1b = p; p += (size_t)INT_ * RP;
  bf16* dv1b = p; p += (size_t)RP * HID;
  bf16* du2b = p; p += (size_t)HID * RP;
  bf16* dv2b = p; p += (size_t)RP * INT_;
  bf16* du3b = p; p += (size_t)INT_ * RP;
  bf16* dv3b = p; p += (size_t)RP * HID;
  bf16* t1b  = p; p += (size_t)T_TOK * RP;
  bf16* t2b  = p; p += (size_t)T_TOK * RP;
  bf16* t3b  = p; p += (size_t)T_TOK * RP;
  bf16* upb  = p; p += (size_t)T_TOK * INT_;
  bf16* zb   = p; p += (size_t)T_TOK * INT_;

  // --- fp32 -> bf16 conversions (weights/activations), zero-padded ranks ---
  k_convert<<<8192, 256, 0, stream>>>(x,  xb,  (long)T_TOK * HID);
  k_convert<<<8192, 256, 0, stream>>>(W1, W1b, (long)INT_ * HID);
  k_convert<<<8192, 256, 0, stream>>>(W2, W2b, (long)HID * INT_);
  k_convert<<<8192, 256, 0, stream>>>(W3, W3b, (long)INT_ * HID);
  k_convert_pad<<<4096, 256, 0, stream>>>(du1, du1b, INT_, RNK, RP,  (long)INT_ * RP);
  k_convert_pad<<<4096, 256, 0, stream>>>(dv1, dv1b, RNK, HID, HID,  (long)RP * HID);
  k_convert_pad<<<4096, 256, 0, stream>>>(du2, du2b, HID, RNK, RP,   (long)HID * RP);
  k_convert_pad<<<4096, 256, 0, stream>>>(dv2, dv2b, RNK, INT_, INT_,(long)RP * INT_);
  k_convert_pad<<<4096, 256, 0, stream>>>(du3, du3b, INT_, RNK, RP,  (long)INT_ * RP);
  k_convert_pad<<<4096, 256, 0, stream>>>(dv3, dv3b, RNK, HID, HID,  (long)RP * HID);

  // --- t3 = x @ dv3^T, t1 = x @ dv1^T  (small N: keep 128^2 kernel) ---
  k_gemm<0><<<dim3(RP / 128, T_TOK / 128), 256, 0, stream>>>(
      xb, dv3b, HID, nullptr, nullptr, 0, RP, t3b, nullptr);
  k_gemm<0><<<dim3(RP / 128, T_TOK / 128), 256, 0, stream>>>(
      xb, dv1b, HID, nullptr, nullptr, 0, RP, t1b, nullptr);

  // --- up = x@W3^T + t3@du3^T  (256^2 8-phase, two-segment K) ---
  k_gemm256<0><<<dim3(INT_ / 256, T_TOK / 256), 512, 0, stream>>>(
      xb, W3b, HID, t3b, du3b, RP, INT_, upb, nullptr);

  // --- z = silu(x@W1^T + t1@du1^T) * up  (fused epilogue) ---
  k_gemm256<1><<<dim3(INT_ / 256, T_TOK / 256), 512, 0, stream>>>(
      xb, W1b, HID, t1b, du1b, RP, INT_, zb, upb);

  // --- t2 = z @ dv2^T  (small N: 128^2 kernel) ---
  k_gemm<0><<<dim3(RP / 128, T_TOK / 128), 256, 0, stream>>>(
      zb, dv2b, INT_, nullptr, nullptr, 0, RP, t2b, nullptr);

  // --- out = z@W2^T + t2@du2^T  (fp32 to d_out) ---
  k_gemm256<2><<<dim3(HID / 256, T_TOK / 256), 512, 0, stream>>>(
      zb, W2b, INT_, t2b, du2b, RP, HID, d_out, nullptr);
}